// Round 12
// baseline (635.743 us; speedup 1.0000x reference)
//
#include <hip/hip_runtime.h>
#include <math.h>

#define KDIM 4096
#define SPLITS 8
#define WAYS 32
#define MAXPB 256
#define NQKV 4608
#define NDENSE 4096
#define KSPLIT 16
#define KRANGE 256

typedef __attribute__((ext_vector_type(8))) short bh8;
typedef __attribute__((ext_vector_type(4))) float f32x4;

__device__ __forceinline__ short f2bf(float x) {
    union { float f; unsigned u; } v; v.f = x;
    unsigned r = v.u + 0x7FFFu + ((v.u >> 16) & 1u);   // RNE
    return (short)(r >> 16);
}
__device__ __forceinline__ float bf2f(short h) {
    union { unsigned u; float f; } v;
    v.u = ((unsigned)(unsigned short)h) << 16;
    return v.f;
}

__device__ __forceinline__ void rope_rotate(float& x0, float& x1, int j, int pos) {
    double inv = pow(10000.0, -(double)j / 32.0);
    double ang = (double)pos * inv;
    float c = (float)cos(ang), s = (float)sin(ang);
    float r0 = x0 * c - x1 * s;
    float r1 = x1 * c + x0 * s;
    x0 = r0; x1 = r1;
}

// Pack hidden[64][4096] f32 -> fragment-major bf16 hi/lo (round-11).
__global__ __launch_bounds__(256) void prep_hilo_pk(
    const float* __restrict__ x, unsigned short* __restrict__ hi,
    unsigned short* __restrict__ lo)
{
    const int id = blockIdx.x * 256 + threadIdx.x;
    const int lane = id & 63;
    const int mtkt = id >> 6;
    const int mt = mtkt & 3;
    const int kt = mtkt >> 2;
    const int m = mt * 16 + (lane & 15);
    const int kk = kt * 32 + (lane >> 4) * 8;
    const float* src = &x[(size_t)m * KDIM + kk];
    float4 a = *(const float4*)src;
    float4 b = *(const float4*)(src + 4);
    float vf[8] = {a.x, a.y, a.z, a.w, b.x, b.y, b.z, b.w};
    unsigned short hbuf[8], lbuf[8];
    #pragma unroll
    for (int e = 0; e < 8; ++e) {
        short hh = f2bf(vf[e]);
        hbuf[e] = (unsigned short)hh;
        lbuf[e] = (unsigned short)f2bf(vf[e] - bf2f(hh));
    }
    *(int4*)&hi[(size_t)id * 8] = *(int4*)hbuf;
    *(int4*)&lo[(size_t)id * 8] = *(int4*)lbuf;
}

// MFMA split-K GEMM (round-11) + rep for PMC A/B vs round-10 protocol.
__global__ __launch_bounds__(256) void gemm_mfma(
    const unsigned short* __restrict__ A_hi, const unsigned short* __restrict__ A_lo,
    const float* __restrict__ W, float* __restrict__ part, int N, int rep)
{
    const int tid = threadIdx.x;
    const int wv = tid >> 6;
    const int l = tid & 63;
    const int lr = l & 15;
    const int h = l >> 4;
    const int n0 = blockIdx.x * 64 + wv * 16;
    const int ks = blockIdx.y;
    const int k0 = ks * KRANGE;

    const float* wrow = &W[(size_t)(n0 + lr) * KDIM + h * 8];
    const size_t abase = (size_t)ks * 8 * 4 * 512 + (size_t)l * 8;

    for (int r = 0; r < rep; ++r) {
        f32x4 acc[4];
        #pragma unroll
        for (int mt = 0; mt < 4; ++mt) acc[mt] = (f32x4){0.f, 0.f, 0.f, 0.f};

        float4 w00, w01, w10, w11;
        bh8 ahc[4], alc[4], ahn[4], aln[4];

        w00 = *(const float4*)&wrow[k0];
        w01 = *(const float4*)&wrow[k0 + 4];
        w10 = *(const float4*)&wrow[k0 + 32];
        w11 = *(const float4*)&wrow[k0 + 36];
        #pragma unroll
        for (int mt = 0; mt < 4; ++mt) {
            ahc[mt] = *(const bh8*)&A_hi[abase + (size_t)mt * 512];
            alc[mt] = *(const bh8*)&A_lo[abase + (size_t)mt * 512];
        }

        auto body = [&](float4& pwa, float4& pwb, int kt) {
            float4 cw0 = pwa, cw1 = pwb;
            if (kt + 2 < 8) {
                pwa = *(const float4*)&wrow[k0 + (kt + 2) * 32];
                pwb = *(const float4*)&wrow[k0 + (kt + 2) * 32 + 4];
            }
            if (kt + 1 < 8) {
                const size_t an = abase + (size_t)(kt + 1) * 2048;
                #pragma unroll
                for (int mt = 0; mt < 4; ++mt) {
                    ahn[mt] = *(const bh8*)&A_hi[an + (size_t)mt * 512];
                    aln[mt] = *(const bh8*)&A_lo[an + (size_t)mt * 512];
                }
            }
            bh8 whi, wlo;
            float wf[8] = {cw0.x, cw0.y, cw0.z, cw0.w, cw1.x, cw1.y, cw1.z, cw1.w};
            #pragma unroll
            for (int e = 0; e < 8; ++e) {
                short hh = f2bf(wf[e]);
                whi[e] = hh;
                wlo[e] = f2bf(wf[e] - bf2f(hh));
            }
            #pragma unroll
            for (int mt = 0; mt < 4; ++mt) {
                acc[mt] = __builtin_amdgcn_mfma_f32_16x16x32_bf16(ahc[mt], whi, acc[mt], 0, 0, 0);
                acc[mt] = __builtin_amdgcn_mfma_f32_16x16x32_bf16(alc[mt], whi, acc[mt], 0, 0, 0);
                acc[mt] = __builtin_amdgcn_mfma_f32_16x16x32_bf16(ahc[mt], wlo, acc[mt], 0, 0, 0);
            }
            if (kt + 1 < 8) {
                #pragma unroll
                for (int mt = 0; mt < 4; ++mt) { ahc[mt] = ahn[mt]; alc[mt] = aln[mt]; }
            }
        };

        for (int kt2 = 0; kt2 < 4; ++kt2) {
            body(w00, w01, kt2 * 2);
            body(w10, w11, kt2 * 2 + 1);
        }

        #pragma unroll
        for (int mt = 0; mt < 4; ++mt) {
            const int m = mt * 16 + h * 4;
            #pragma unroll
            for (int j = 0; j < 4; ++j)
                part[((size_t)ks * 64 + m + j) * N + n0 + lr] = acc[mt][j];
        }
    }
}

__global__ __launch_bounds__(256) void reduce_qkv(
    const float* __restrict__ part, const int* __restrict__ lens,
    float* __restrict__ q_rope, float* __restrict__ knew, float* __restrict__ vnew)
{
    const int b = blockIdx.y;
    const int c0 = (blockIdx.x * 256 + threadIdx.x) * 2;
    float x0 = 0.f, x1 = 0.f;
    #pragma unroll
    for (int ks = 0; ks < KSPLIT; ++ks) {
        float2 v = *(const float2*)&part[((size_t)ks * 64 + b) * NQKV + c0];
        x0 += v.x; x1 += v.y;
    }
    const int pos = lens[b] - 1;
    if (c0 < 4096) {
        const int d = c0 & 127;
        if (d < 64) rope_rotate(x0, x1, d >> 1, pos);
        q_rope[(size_t)b * 4096 + c0] = x0;
        q_rope[(size_t)b * 4096 + c0 + 1] = x1;
    } else if (c0 < 4352) {
        const int kidx = c0 - 4096, kh = kidx >> 7, d = kidx & 127;
        if (d < 64) rope_rotate(x0, x1, d >> 1, pos);
        knew[(b * 2 + kh) * 128 + d] = x0;
        knew[(b * 2 + kh) * 128 + d + 1] = x1;
    } else {
        const int vidx = c0 - 4352, kh = vidx >> 7, d = vidx & 127;
        vnew[(b * 2 + kh) * 128 + d] = x0;
        vnew[(b * 2 + kh) * 128 + d + 1] = x1;
    }
}

// MFMA flash-decode (round-5/11 known-best) + rep for first attn counters.
__global__ __launch_bounds__(256) void attn_mfma(
    const float* __restrict__ qr, const float* __restrict__ knew,
    const float* __restrict__ vnew, const float* __restrict__ kcache,
    const float* __restrict__ vcache, const int* __restrict__ bt,
    const int* __restrict__ lens, float* __restrict__ pO, float* __restrict__ pML,
    int rep)
{
    const int split = blockIdx.x;
    const int kh = blockIdx.y;
    const int b = blockIdx.z;
    const int tid = threadIdx.x;
    const int wv = tid >> 6;
    const int l = tid & 63;
    const int g = l & 15;
    const int h = l >> 4;
    const int way = split * 4 + wv;

    __shared__ unsigned int sP[4][256];
    __shared__ float sO[3][16][132];
    __shared__ float sML[3][2][16];

    const int len = lens[b];
    const int nchunks = (len + 31) >> 5;
    const size_t nbase = ((size_t)(b * 2 + kh)) * 128;
    const float scale = 0.08838834764831845f;

    for (int r = 0; r < rep; ++r) {
        bh8 qf[4];
        {
            const float* qrow = &qr[((size_t)(b * 32 + kh * 16 + g)) * 128 + h * 8];
            #pragma unroll
            for (int dc = 0; dc < 4; ++dc) {
                float4 a = *(const float4*)&qrow[dc * 32];
                float4 c = *(const float4*)&qrow[dc * 32 + 4];
                qf[dc][0] = f2bf(a.x * scale); qf[dc][1] = f2bf(a.y * scale);
                qf[dc][2] = f2bf(a.z * scale); qf[dc][3] = f2bf(a.w * scale);
                qf[dc][4] = f2bf(c.x * scale); qf[dc][5] = f2bf(c.y * scale);
                qf[dc][6] = f2bf(c.z * scale); qf[dc][7] = f2bf(c.w * scale);
            }
        }

        float m = -INFINITY, lacc = 0.f;
        f32x4 oacc[8];
        #pragma unroll
        for (int dt = 0; dt < 8; ++dt) oacc[dt] = (f32x4){0.f, 0.f, 0.f, 0.f};

        for (int c = way; c < nchunks; c += WAYS) {
            const int s0 = c * 32;
            const int blk0 = bt[b * MAXPB + 2 * c];
            const int blk1 = bt[b * MAXPB + 2 * c + 1];

            const float* rowK0 = (s0 + g == len - 1) ? &knew[nbase]
                : &kcache[(((size_t)blk0 * 16 + g) * 2 + kh) * 128];
            const float* rowK1 = (s0 + 16 + g == len - 1) ? &knew[nbase]
                : &kcache[(((size_t)blk1 * 16 + g) * 2 + kh) * 128];
            float4 k0[8], k1[8];
            #pragma unroll
            for (int dc = 0; dc < 4; ++dc) {
                k0[2*dc]   = *(const float4*)&rowK0[dc * 32 + h * 8];
                k0[2*dc+1] = *(const float4*)&rowK0[dc * 32 + h * 8 + 4];
                k1[2*dc]   = *(const float4*)&rowK1[dc * 32 + h * 8];
                k1[2*dc+1] = *(const float4*)&rowK1[dc * 32 + h * 8 + 4];
            }

            float vv[8][8];
            #pragma unroll
            for (int e = 0; e < 8; ++e) {
                const int p = h * 8 + e;
                const int s = s0 + p;
                const float* rowV = (s == len - 1) ? &vnew[nbase]
                    : &vcache[(((size_t)(p < 16 ? blk0 : blk1) * 16 + (p & 15)) * 2 + kh) * 128];
                #pragma unroll
                for (int dt = 0; dt < 8; ++dt)
                    vv[e][dt] = rowV[dt * 16 + g];
            }

            f32x4 sa0 = (f32x4){0.f,0.f,0.f,0.f};
            f32x4 sa1 = (f32x4){0.f,0.f,0.f,0.f};
            #pragma unroll
            for (int dc = 0; dc < 4; ++dc) {
                bh8 a0, a1;
                a0[0]=f2bf(k0[2*dc].x);   a0[1]=f2bf(k0[2*dc].y);
                a0[2]=f2bf(k0[2*dc].z);   a0[3]=f2bf(k0[2*dc].w);
                a0[4]=f2bf(k0[2*dc+1].x); a0[5]=f2bf(k0[2*dc+1].y);
                a0[6]=f2bf(k0[2*dc+1].z); a0[7]=f2bf(k0[2*dc+1].w);
                a1[0]=f2bf(k1[2*dc].x);   a1[1]=f2bf(k1[2*dc].y);
                a1[2]=f2bf(k1[2*dc].z);   a1[3]=f2bf(k1[2*dc].w);
                a1[4]=f2bf(k1[2*dc+1].x); a1[5]=f2bf(k1[2*dc+1].y);
                a1[6]=f2bf(k1[2*dc+1].z); a1[7]=f2bf(k1[2*dc+1].w);
                sa0 = __builtin_amdgcn_mfma_f32_16x16x32_bf16(a0, qf[dc], sa0, 0, 0, 0);
                sa1 = __builtin_amdgcn_mfma_f32_16x16x32_bf16(a1, qf[dc], sa1, 0, 0, 0);
            }

            float sc[8];
            #pragma unroll
            for (int j = 0; j < 4; ++j) {
                sc[j]     = (s0 + 4*h + j      < len) ? sa0[j] : -INFINITY;
                sc[4 + j] = (s0 + 16 + 4*h + j < len) ? sa1[j] : -INFINITY;
            }
            float tmax = sc[0];
            #pragma unroll
            for (int j = 1; j < 8; ++j) tmax = fmaxf(tmax, sc[j]);
            tmax = fmaxf(tmax, __shfl_xor(tmax, 16));
            tmax = fmaxf(tmax, __shfl_xor(tmax, 32));
            const float m_new = fmaxf(m, tmax);
            const float corr = expf(m - m_new);
            float pe[8], ls = 0.f;
            #pragma unroll
            for (int j = 0; j < 8; ++j) { pe[j] = expf(sc[j] - m_new); ls += pe[j]; }
            ls += __shfl_xor(ls, 16);
            ls += __shfl_xor(ls, 32);
            lacc = lacc * corr + ls;
            m = m_new;
            #pragma unroll
            for (int dt = 0; dt < 8; ++dt) {
                oacc[dt][0] *= corr; oacc[dt][1] *= corr;
                oacc[dt][2] *= corr; oacc[dt][3] *= corr;
            }

            unsigned int* myP = sP[wv];
            #pragma unroll
            for (int ph = 0; ph < 2; ++ph)
                #pragma unroll
                for (int t2 = 0; t2 < 2; ++t2) {
                    unsigned lo = (unsigned short)f2bf(pe[ph*4 + 2*t2]);
                    unsigned hi = (unsigned short)f2bf(pe[ph*4 + 2*t2 + 1]);
                    myP[g * 16 + ph * 8 + 2 * h + t2] = lo | (hi << 16);
                }
            asm volatile("s_waitcnt lgkmcnt(0)" ::: "memory");
            bh8 pf = *(const bh8*)&myP[g * 16 + 4 * h];

            #pragma unroll
            for (int dt = 0; dt < 8; ++dt) {
                bh8 av;
                #pragma unroll
                for (int e = 0; e < 8; ++e) av[e] = f2bf(vv[e][dt]);
                oacc[dt] = __builtin_amdgcn_mfma_f32_16x16x32_bf16(av, pf, oacc[dt], 0, 0, 0);
            }
        }

        if (wv > 0) {
            #pragma unroll
            for (int dt = 0; dt < 8; ++dt)
                #pragma unroll
                for (int j = 0; j < 4; ++j)
                    sO[wv-1][g][dt*16 + 4*h + j] = oacc[dt][j];
            if (l < 16) {
                sML[wv-1][0][g] = m;
                sML[wv-1][1][g] = lacc;
            }
        }
        __syncthreads();
        if (wv == 0) {
            float M = m;
            #pragma unroll
            for (int i = 0; i < 3; ++i) M = fmaxf(M, sML[i][0][g]);
            const float w0 = expf(m - M);
            float L = lacc * w0;
            float wi[3];
            #pragma unroll
            for (int i = 0; i < 3; ++i) {
                wi[i] = expf(sML[i][0][g] - M);
                L += sML[i][1][g] * wi[i];
            }
            size_t base = ((((size_t)(b * 2 + kh)) * SPLITS + split) * 16 + g) * 128;
            #pragma unroll
            for (int dt = 0; dt < 8; ++dt)
                #pragma unroll
                for (int j = 0; j < 4; ++j) {
                    float o = oacc[dt][j] * w0;
                    #pragma unroll
                    for (int i = 0; i < 3; ++i)
                        o += sO[i][g][dt*16 + 4*h + j] * wi[i];
                    pO[base + dt*16 + 4*h + j] = o;
                }
            if (l < 16) {
                size_t mb = ((((size_t)(b * 2 + kh)) * SPLITS + split) * 16 + g) * 2;
                pML[mb] = M;
                pML[mb + 1] = L;
            }
        }
        __syncthreads();   // rep-loop isolation: sO/sML reused next iteration
    }
}

// Combine splits; emit dense-GEMM input in PACKED frag-major hi/lo layout.
__global__ __launch_bounds__(256) void attn_combine(
    const float* __restrict__ pO, const float* __restrict__ pML,
    unsigned short* __restrict__ a_hi, unsigned short* __restrict__ a_lo)
{
    const int bk = blockIdx.x;
    const int tid = threadIdx.x;
    const int g = tid >> 4;
    const int dh = tid & 15;

    float ms[SPLITS], ls[SPLITS];
    float M = -INFINITY;
    #pragma unroll
    for (int s = 0; s < SPLITS; ++s) {
        size_t mb = (((size_t)bk * SPLITS + s) * 16 + g) * 2;
        ms[s] = pML[mb]; ls[s] = pML[mb + 1];
        M = fmaxf(M, ms[s]);
    }
    float L = 0.f;
    #pragma unroll
    for (int s = 0; s < SPLITS; ++s) L += ls[s] * expf(ms[s] - M);

    float acc[8] = {0, 0, 0, 0, 0, 0, 0, 0};
    #pragma unroll
    for (int s = 0; s < SPLITS; ++s) {
        float wgt = expf(ms[s] - M);
        const float* src = &pO[(((size_t)bk * SPLITS + s) * 16 + g) * 128 + dh * 8];
        #pragma unroll
        for (int r = 0; r < 8; ++r) acc[r] += wgt * src[r];
    }
    const float invL = 1.f / L;
    const int b = bk >> 1, kh = bk & 1;
    const int k0 = (kh * 16 + g) * 128 + dh * 8;
    const int kt = k0 >> 5;
    const int h2 = dh & 3;
    const size_t didx = (((size_t)(kt * 4 + (b >> 4))) * 64 + h2 * 16 + (b & 15)) * 8;
    unsigned short hbuf[8], lbuf[8];
    #pragma unroll
    for (int r = 0; r < 8; ++r) {
        float o = acc[r] * invL;
        short hh = f2bf(o);
        hbuf[r] = (unsigned short)hh;
        lbuf[r] = (unsigned short)f2bf(o - bf2f(hh));
    }
    *(int4*)&a_hi[didx] = *(int4*)hbuf;
    *(int4*)&a_lo[didx] = *(int4*)lbuf;
}

__global__ __launch_bounds__(256) void reduce_dense(
    const float* __restrict__ part, float* __restrict__ out)
{
    const int b = blockIdx.y;
    const int col = (blockIdx.x * 256 + threadIdx.x) * 4;
    float4 s = make_float4(0.f, 0.f, 0.f, 0.f);
    #pragma unroll
    for (int ks = 0; ks < KSPLIT; ++ks) {
        float4 v = *(const float4*)&part[((size_t)ks * 64 + b) * NDENSE + col];
        s.x += v.x; s.y += v.y; s.z += v.z; s.w += v.w;
    }
    *(float4*)&out[(size_t)b * 4096 + col] = s;
}

extern "C" void kernel_launch(void* const* d_in, const int* in_sizes, int n_in,
                              void* d_out, int out_size, void* d_ws, size_t ws_size,
                              hipStream_t stream) {
    const float* hidden = (const float*)d_in[0];
    const float* wqkv   = (const float*)d_in[1];
    const float* wdense = (const float*)d_in[2];
    const float* kcache = (const float*)d_in[3];
    const float* vcache = (const float*)d_in[4];
    const int*   bt     = (const int*)d_in[5];
    const int*   lens   = (const int*)d_in[7];
    float* out = (float*)d_out;

    float* ws     = (float*)d_ws;
    float* q_rope = ws;                       // 262144 f
    float* k_new  = ws + 262144;              // 16384 f
    float* v_new  = ws + 278528;              // 16384 f
    unsigned short* A_hi = (unsigned short*)(ws + 294912);   // packed
    unsigned short* A_lo = A_hi + 262144;                    // packed
    float* regX   = ws + 557056;              // partials / pO
    float* pO     = regX;
    float* pML    = ws + 5275648;             // 32768 f

    prep_hilo_pk<<<dim3(128), dim3(256), 0, stream>>>(hidden, A_hi, A_lo);
    gemm_mfma<<<dim3(NQKV / 64, KSPLIT), dim3(256), 0, stream>>>(
        A_hi, A_lo, wqkv, regX, NQKV, 8);
    reduce_qkv<<<dim3(9, 64), dim3(256), 0, stream>>>(
        regX, lens, q_rope, k_new, v_new);
    attn_mfma<<<dim3(SPLITS, 2, 64), dim3(256), 0, stream>>>(
        q_rope, k_new, v_new, kcache, vcache, bt, lens, pO, pML, 6);
    attn_combine<<<dim3(128), dim3(256), 0, stream>>>(pO, pML, A_hi, A_lo);
    gemm_mfma<<<dim3(NDENSE / 64, KSPLIT), dim3(256), 0, stream>>>(
        A_hi, A_lo, wdense, regX, NDENSE, 8);
    reduce_dense<<<dim3(4, 64), dim3(256), 0, stream>>>(regX, out);
}

// Round 13
// 288.167 us; speedup vs baseline: 2.2062x; 2.2062x over previous
//
#include <hip/hip_runtime.h>
#include <math.h>

#define KDIM 4096
#define SPLITS 8
#define WAYS 32
#define MAXPB 256
#define NQKV 4608
#define NDENSE 4096
#define KSPLIT 16
#define KRANGE 256

typedef __attribute__((ext_vector_type(8))) short bh8;
typedef __attribute__((ext_vector_type(4))) float f32x4;

__device__ __forceinline__ short f2bf(float x) {
    union { float f; unsigned u; } v; v.f = x;
    unsigned r = v.u + 0x7FFFu + ((v.u >> 16) & 1u);   // RNE
    return (short)(r >> 16);
}
__device__ __forceinline__ float bf2f(short h) {
    union { unsigned u; float f; } v;
    v.u = ((unsigned)(unsigned short)h) << 16;
    return v.f;
}

__device__ __forceinline__ void rope_rotate(float& x0, float& x1, int j, int pos) {
    double inv = pow(10000.0, -(double)j / 32.0);
    double ang = (double)pos * inv;
    float c = (float)cos(ang), s = (float)sin(ang);
    float r0 = x0 * c - x1 * s;
    float r1 = x1 * c + x0 * s;
    x0 = r0; x1 = r1;
}

// Pack hidden[64][4096] f32 -> fragment-major bf16 hi/lo (round-11).
__global__ __launch_bounds__(256) void prep_hilo_pk(
    const float* __restrict__ x, unsigned short* __restrict__ hi,
    unsigned short* __restrict__ lo)
{
    const int id = blockIdx.x * 256 + threadIdx.x;
    const int lane = id & 63;
    const int mtkt = id >> 6;
    const int mt = mtkt & 3;
    const int kt = mtkt >> 2;
    const int m = mt * 16 + (lane & 15);
    const int kk = kt * 32 + (lane >> 4) * 8;
    const float* src = &x[(size_t)m * KDIM + kk];
    float4 a = *(const float4*)src;
    float4 b = *(const float4*)(src + 4);
    float vf[8] = {a.x, a.y, a.z, a.w, b.x, b.y, b.z, b.w};
    unsigned short hbuf[8], lbuf[8];
    #pragma unroll
    for (int e = 0; e < 8; ++e) {
        short hh = f2bf(vf[e]);
        hbuf[e] = (unsigned short)hh;
        lbuf[e] = (unsigned short)f2bf(vf[e] - bf2f(hh));
    }
    *(int4*)&hi[(size_t)id * 8] = *(int4*)hbuf;
    *(int4*)&lo[(size_t)id * 8] = *(int4*)lbuf;
}

// MFMA split-K GEMM (round-11 verbatim, no rep).
__global__ __launch_bounds__(256) void gemm_mfma(
    const unsigned short* __restrict__ A_hi, const unsigned short* __restrict__ A_lo,
    const float* __restrict__ W, float* __restrict__ part, int N)
{
    const int tid = threadIdx.x;
    const int wv = tid >> 6;
    const int l = tid & 63;
    const int lr = l & 15;
    const int h = l >> 4;
    const int n0 = blockIdx.x * 64 + wv * 16;
    const int ks = blockIdx.y;
    const int k0 = ks * KRANGE;

    const float* wrow = &W[(size_t)(n0 + lr) * KDIM + h * 8];
    const size_t abase = (size_t)ks * 8 * 4 * 512 + (size_t)l * 8;

    f32x4 acc[4];
    #pragma unroll
    for (int mt = 0; mt < 4; ++mt) acc[mt] = (f32x4){0.f, 0.f, 0.f, 0.f};

    float4 w00, w01, w10, w11;
    bh8 ahc[4], alc[4], ahn[4], aln[4];

    w00 = *(const float4*)&wrow[k0];
    w01 = *(const float4*)&wrow[k0 + 4];
    w10 = *(const float4*)&wrow[k0 + 32];
    w11 = *(const float4*)&wrow[k0 + 36];
    #pragma unroll
    for (int mt = 0; mt < 4; ++mt) {
        ahc[mt] = *(const bh8*)&A_hi[abase + (size_t)mt * 512];
        alc[mt] = *(const bh8*)&A_lo[abase + (size_t)mt * 512];
    }

    auto body = [&](float4& pwa, float4& pwb, int kt) {
        float4 cw0 = pwa, cw1 = pwb;
        if (kt + 2 < 8) {
            pwa = *(const float4*)&wrow[k0 + (kt + 2) * 32];
            pwb = *(const float4*)&wrow[k0 + (kt + 2) * 32 + 4];
        }
        if (kt + 1 < 8) {
            const size_t an = abase + (size_t)(kt + 1) * 2048;
            #pragma unroll
            for (int mt = 0; mt < 4; ++mt) {
                ahn[mt] = *(const bh8*)&A_hi[an + (size_t)mt * 512];
                aln[mt] = *(const bh8*)&A_lo[an + (size_t)mt * 512];
            }
        }
        bh8 whi, wlo;
        float wf[8] = {cw0.x, cw0.y, cw0.z, cw0.w, cw1.x, cw1.y, cw1.z, cw1.w};
        #pragma unroll
        for (int e = 0; e < 8; ++e) {
            short hh = f2bf(wf[e]);
            whi[e] = hh;
            wlo[e] = f2bf(wf[e] - bf2f(hh));
        }
        #pragma unroll
        for (int mt = 0; mt < 4; ++mt) {
            acc[mt] = __builtin_amdgcn_mfma_f32_16x16x32_bf16(ahc[mt], whi, acc[mt], 0, 0, 0);
            acc[mt] = __builtin_amdgcn_mfma_f32_16x16x32_bf16(alc[mt], whi, acc[mt], 0, 0, 0);
            acc[mt] = __builtin_amdgcn_mfma_f32_16x16x32_bf16(ahc[mt], wlo, acc[mt], 0, 0, 0);
        }
        if (kt + 1 < 8) {
            #pragma unroll
            for (int mt = 0; mt < 4; ++mt) { ahc[mt] = ahn[mt]; alc[mt] = aln[mt]; }
        }
    };

    for (int kt2 = 0; kt2 < 4; ++kt2) {
        body(w00, w01, kt2 * 2);
        body(w10, w11, kt2 * 2 + 1);
    }

    #pragma unroll
    for (int mt = 0; mt < 4; ++mt) {
        const int m = mt * 16 + h * 4;
        #pragma unroll
        for (int j = 0; j < 4; ++j)
            part[((size_t)ks * 64 + m + j) * N + n0 + lr] = acc[mt][j];
    }
}

__global__ __launch_bounds__(256) void reduce_qkv(
    const float* __restrict__ part, const int* __restrict__ lens,
    float* __restrict__ q_rope, float* __restrict__ knew, float* __restrict__ vnew)
{
    const int b = blockIdx.y;
    const int c0 = (blockIdx.x * 256 + threadIdx.x) * 2;
    float x0 = 0.f, x1 = 0.f;
    #pragma unroll
    for (int ks = 0; ks < KSPLIT; ++ks) {
        float2 v = *(const float2*)&part[((size_t)ks * 64 + b) * NQKV + c0];
        x0 += v.x; x1 += v.y;
    }
    const int pos = lens[b] - 1;
    if (c0 < 4096) {
        const int d = c0 & 127;
        if (d < 64) rope_rotate(x0, x1, d >> 1, pos);
        q_rope[(size_t)b * 4096 + c0] = x0;
        q_rope[(size_t)b * 4096 + c0 + 1] = x1;
    } else if (c0 < 4352) {
        const int kidx = c0 - 4096, kh = kidx >> 7, d = kidx & 127;
        if (d < 64) rope_rotate(x0, x1, d >> 1, pos);
        knew[(b * 2 + kh) * 128 + d] = x0;
        knew[(b * 2 + kh) * 128 + d + 1] = x1;
    } else {
        const int vidx = c0 - 4352, kh = vidx >> 7, d = vidx & 127;
        vnew[(b * 2 + kh) * 128 + d] = x0;
        vnew[(b * 2 + kh) * 128 + d + 1] = x1;
    }
}

// MFMA flash-decode, 32-way independent partials (no in-block merge).
// V converted to bf16 at load (packed) to cut VGPR; launch_bounds(256,5)
// caps VGPR at 102 -> 5 waves/SIMD (was 116 -> 4).
__global__ __launch_bounds__(256, 5) void attn_mfma(
    const float* __restrict__ qr, const float* __restrict__ knew,
    const float* __restrict__ vnew, const float* __restrict__ kcache,
    const float* __restrict__ vcache, const int* __restrict__ bt,
    const int* __restrict__ lens, float* __restrict__ pO, float* __restrict__ pML)
{
    const int split = blockIdx.x;
    const int kh = blockIdx.y;
    const int b = blockIdx.z;
    const int tid = threadIdx.x;
    const int wv = tid >> 6;
    const int l = tid & 63;
    const int g = l & 15;
    const int h = l >> 4;
    const int way = split * 4 + wv;

    __shared__ unsigned int sP[4][256];

    const int len = lens[b];
    const int nchunks = (len + 31) >> 5;   // len>=1024 -> nchunks>=32=WAYS
    const size_t nbase = ((size_t)(b * 2 + kh)) * 128;

    const float scale = 0.08838834764831845f;
    bh8 qf[4];
    {
        const float* qrow = &qr[((size_t)(b * 32 + kh * 16 + g)) * 128 + h * 8];
        #pragma unroll
        for (int dc = 0; dc < 4; ++dc) {
            float4 a = *(const float4*)&qrow[dc * 32];
            float4 c = *(const float4*)&qrow[dc * 32 + 4];
            qf[dc][0] = f2bf(a.x * scale); qf[dc][1] = f2bf(a.y * scale);
            qf[dc][2] = f2bf(a.z * scale); qf[dc][3] = f2bf(a.w * scale);
            qf[dc][4] = f2bf(c.x * scale); qf[dc][5] = f2bf(c.y * scale);
            qf[dc][6] = f2bf(c.z * scale); qf[dc][7] = f2bf(c.w * scale);
        }
    }

    float m = -INFINITY, lacc = 0.f;
    f32x4 oacc[8];
    #pragma unroll
    for (int dt = 0; dt < 8; ++dt) oacc[dt] = (f32x4){0.f, 0.f, 0.f, 0.f};

    for (int c = way; c < nchunks; c += WAYS) {
        const int s0 = c * 32;
        const int blk0 = bt[b * MAXPB + 2 * c];
        const int blk1 = bt[b * MAXPB + 2 * c + 1];

        // ---- K loads (f32 staging, converted after)
        const float* rowK0 = (s0 + g == len - 1) ? &knew[nbase]
            : &kcache[(((size_t)blk0 * 16 + g) * 2 + kh) * 128];
        const float* rowK1 = (s0 + 16 + g == len - 1) ? &knew[nbase]
            : &kcache[(((size_t)blk1 * 16 + g) * 2 + kh) * 128];
        float4 k0[8], k1[8];
        #pragma unroll
        for (int dc = 0; dc < 4; ++dc) {
            k0[2*dc]   = *(const float4*)&rowK0[dc * 32 + h * 8];
            k0[2*dc+1] = *(const float4*)&rowK0[dc * 32 + h * 8 + 4];
            k1[2*dc]   = *(const float4*)&rowK1[dc * 32 + h * 8];
            k1[2*dc+1] = *(const float4*)&rowK1[dc * 32 + h * 8 + 4];
        }

        // ---- V loads: convert to bf16 at load, packed [dt][4x u32]
        unsigned vw[8][4];
        #pragma unroll
        for (int e = 0; e < 8; ++e) {
            const int p = h * 8 + e;
            const int s = s0 + p;
            const float* rowV = (s == len - 1) ? &vnew[nbase]
                : &vcache[(((size_t)(p < 16 ? blk0 : blk1) * 16 + (p & 15)) * 2 + kh) * 128];
            #pragma unroll
            for (int dt = 0; dt < 8; ++dt) {
                unsigned short bb = (unsigned short)f2bf(rowV[dt * 16 + g]);
                if (e & 1) vw[dt][e >> 1] |= ((unsigned)bb << 16);
                else       vw[dt][e >> 1] = bb;
            }
        }

        // ---- QK^T
        f32x4 sa0 = (f32x4){0.f,0.f,0.f,0.f};
        f32x4 sa1 = (f32x4){0.f,0.f,0.f,0.f};
        #pragma unroll
        for (int dc = 0; dc < 4; ++dc) {
            bh8 a0, a1;
            a0[0]=f2bf(k0[2*dc].x);   a0[1]=f2bf(k0[2*dc].y);
            a0[2]=f2bf(k0[2*dc].z);   a0[3]=f2bf(k0[2*dc].w);
            a0[4]=f2bf(k0[2*dc+1].x); a0[5]=f2bf(k0[2*dc+1].y);
            a0[6]=f2bf(k0[2*dc+1].z); a0[7]=f2bf(k0[2*dc+1].w);
            a1[0]=f2bf(k1[2*dc].x);   a1[1]=f2bf(k1[2*dc].y);
            a1[2]=f2bf(k1[2*dc].z);   a1[3]=f2bf(k1[2*dc].w);
            a1[4]=f2bf(k1[2*dc+1].x); a1[5]=f2bf(k1[2*dc+1].y);
            a1[6]=f2bf(k1[2*dc+1].z); a1[7]=f2bf(k1[2*dc+1].w);
            sa0 = __builtin_amdgcn_mfma_f32_16x16x32_bf16(a0, qf[dc], sa0, 0, 0, 0);
            sa1 = __builtin_amdgcn_mfma_f32_16x16x32_bf16(a1, qf[dc], sa1, 0, 0, 0);
        }

        // ---- online softmax
        float sc[8];
        #pragma unroll
        for (int j = 0; j < 4; ++j) {
            sc[j]     = (s0 + 4*h + j      < len) ? sa0[j] : -INFINITY;
            sc[4 + j] = (s0 + 16 + 4*h + j < len) ? sa1[j] : -INFINITY;
        }
        float tmax = sc[0];
        #pragma unroll
        for (int j = 1; j < 8; ++j) tmax = fmaxf(tmax, sc[j]);
        tmax = fmaxf(tmax, __shfl_xor(tmax, 16));
        tmax = fmaxf(tmax, __shfl_xor(tmax, 32));
        const float m_new = fmaxf(m, tmax);
        const float corr = expf(m - m_new);
        float pe[8], ls = 0.f;
        #pragma unroll
        for (int j = 0; j < 8; ++j) { pe[j] = expf(sc[j] - m_new); ls += pe[j]; }
        ls += __shfl_xor(ls, 16);
        ls += __shfl_xor(ls, 32);
        lacc = lacc * corr + ls;
        m = m_new;
        #pragma unroll
        for (int dt = 0; dt < 8; ++dt) {
            oacc[dt][0] *= corr; oacc[dt][1] *= corr;
            oacc[dt][2] *= corr; oacc[dt][3] *= corr;
        }

        // ---- P relay via LDS (wave-local)
        unsigned int* myP = sP[wv];
        #pragma unroll
        for (int ph = 0; ph < 2; ++ph)
            #pragma unroll
            for (int t2 = 0; t2 < 2; ++t2) {
                unsigned lo = (unsigned short)f2bf(pe[ph*4 + 2*t2]);
                unsigned hi = (unsigned short)f2bf(pe[ph*4 + 2*t2 + 1]);
                myP[g * 16 + ph * 8 + 2 * h + t2] = lo | (hi << 16);
            }
        asm volatile("s_waitcnt lgkmcnt(0)" ::: "memory");
        bh8 pf = *(const bh8*)&myP[g * 16 + 4 * h];

        // ---- PV (V already bf16-packed)
        #pragma unroll
        for (int dt = 0; dt < 8; ++dt) {
            union { unsigned u[4]; bh8 v; } cvt;
            cvt.u[0] = vw[dt][0]; cvt.u[1] = vw[dt][1];
            cvt.u[2] = vw[dt][2]; cvt.u[3] = vw[dt][3];
            oacc[dt] = __builtin_amdgcn_mfma_f32_16x16x32_bf16(cvt.v, pf, oacc[dt], 0, 0, 0);
        }
    }

    // ---- every wave writes its own way slot (no block merge)
    size_t base = ((((size_t)(b * 2 + kh)) * 32 + way) * 16 + g) * 128;
    #pragma unroll
    for (int dt = 0; dt < 8; ++dt)
        #pragma unroll
        for (int j = 0; j < 4; ++j)
            pO[base + dt*16 + 4*h + j] = oacc[dt][j];
    if (l < 16) {
        size_t mb = ((((size_t)(b * 2 + kh)) * 32 + way) * 16 + g) * 2;
        pML[mb] = m;
        pML[mb + 1] = lacc;
    }
}

// Combine 32 ways; emit dense-GEMM input in PACKED frag-major hi/lo layout.
// Grid (128,2) x 128 threads: block = (bk, d-half), thread = (g, dq).
__global__ __launch_bounds__(128) void attn_combine(
    const float* __restrict__ pO, const float* __restrict__ pML,
    unsigned short* __restrict__ a_hi, unsigned short* __restrict__ a_lo)
{
    const int bk = blockIdx.x;
    const int half = blockIdx.y;
    const int tid = threadIdx.x;
    const int g = tid >> 3;
    const int dh = half * 8 + (tid & 7);

    float M = -INFINITY;
    #pragma unroll
    for (int s = 0; s < 32; ++s)
        M = fmaxf(M, pML[(((size_t)bk * 32 + s) * 16 + g) * 2]);

    float L = 0.f;
    float acc[8] = {0, 0, 0, 0, 0, 0, 0, 0};
    #pragma unroll 4
    for (int s = 0; s < 32; ++s) {
        size_t mb = (((size_t)bk * 32 + s) * 16 + g) * 2;
        float w = expf(pML[mb] - M);
        L += pML[mb + 1] * w;
        const float* src = &pO[(((size_t)bk * 32 + s) * 16 + g) * 128 + dh * 8];
        #pragma unroll
        for (int r = 0; r < 8; ++r) acc[r] += w * src[r];
    }
    const float invL = 1.f / L;
    const int b = bk >> 1, kh = bk & 1;
    const int k0 = (kh * 16 + g) * 128 + dh * 8;
    const int kt = k0 >> 5;
    const int h2 = dh & 3;
    const size_t didx = (((size_t)(kt * 4 + (b >> 4))) * 64 + h2 * 16 + (b & 15)) * 8;
    unsigned short hbuf[8], lbuf[8];
    #pragma unroll
    for (int r = 0; r < 8; ++r) {
        float o = acc[r] * invL;
        short hh = f2bf(o);
        hbuf[r] = (unsigned short)hh;
        lbuf[r] = (unsigned short)f2bf(o - bf2f(hh));
    }
    *(int4*)&a_hi[didx] = *(int4*)hbuf;
    *(int4*)&a_lo[didx] = *(int4*)lbuf;
}

__global__ __launch_bounds__(256) void reduce_dense(
    const float* __restrict__ part, float* __restrict__ out)
{
    const int b = blockIdx.y;
    const int col = (blockIdx.x * 256 + threadIdx.x) * 4;
    float4 s = make_float4(0.f, 0.f, 0.f, 0.f);
    #pragma unroll
    for (int ks = 0; ks < KSPLIT; ++ks) {
        float4 v = *(const float4*)&part[((size_t)ks * 64 + b) * NDENSE + col];
        s.x += v.x; s.y += v.y; s.z += v.z; s.w += v.w;
    }
    *(float4*)&out[(size_t)b * 4096 + col] = s;
}

extern "C" void kernel_launch(void* const* d_in, const int* in_sizes, int n_in,
                              void* d_out, int out_size, void* d_ws, size_t ws_size,
                              hipStream_t stream) {
    const float* hidden = (const float*)d_in[0];
    const float* wqkv   = (const float*)d_in[1];
    const float* wdense = (const float*)d_in[2];
    const float* kcache = (const float*)d_in[3];
    const float* vcache = (const float*)d_in[4];
    const int*   bt     = (const int*)d_in[5];
    const int*   lens   = (const int*)d_in[7];
    float* out = (float*)d_out;

    float* ws     = (float*)d_ws;
    float* q_rope = ws;                       // 262144 f
    float* k_new  = ws + 262144;              // 16384 f
    float* v_new  = ws + 278528;              // 16384 f
    unsigned short* A_hi = (unsigned short*)(ws + 294912);   // packed
    unsigned short* A_lo = A_hi + 262144;                    // packed
    float* regX   = ws + 557056;              // gemm partials (<=4718592 f) / pO
    float* pO     = regX;                     // 64*2*32*16*128 = 8388608 f
    float* pML    = ws + 557056 + 8388608;    // 131072 f
    // total ws use: 9076736 floats = 36.3 MB (no overlap: partials end at 5275648)

    prep_hilo_pk<<<dim3(128), dim3(256), 0, stream>>>(hidden, A_hi, A_lo);
    gemm_mfma<<<dim3(NQKV / 64, KSPLIT), dim3(256), 0, stream>>>(
        A_hi, A_lo, wqkv, regX, NQKV);
    reduce_qkv<<<dim3(9, 64), dim3(256), 0, stream>>>(
        regX, lens, q_rope, k_new, v_new);
    attn_mfma<<<dim3(SPLITS, 2, 64), dim3(256), 0, stream>>>(
        q_rope, k_new, v_new, kcache, vcache, bt, lens, pO, pML);
    attn_combine<<<dim3(128, 2), dim3(128), 0, stream>>>(pO, pML, A_hi, A_lo);
    gemm_mfma<<<dim3(NDENSE / 64, KSPLIT), dim3(256), 0, stream>>>(
        A_hi, A_lo, wdense, regX, NDENSE);
    reduce_dense<<<dim3(4, 64), dim3(256), 0, stream>>>(regX, out);
}

// Round 14
// 175.504 us; speedup vs baseline: 3.6224x; 1.6419x over previous
//
#include <hip/hip_runtime.h>
#include <math.h>

#define KDIM 4096
#define SPLITS 8
#define WAYS 32
#define MAXPB 256
#define NQKV 4608
#define NDENSE 4096
#define KSPLIT 16
#define KRANGE 256

typedef __attribute__((ext_vector_type(8))) short bh8;
typedef __attribute__((ext_vector_type(4))) float f32x4;

__device__ __forceinline__ short f2bf(float x) {
    union { float f; unsigned u; } v; v.f = x;
    unsigned r = v.u + 0x7FFFu + ((v.u >> 16) & 1u);   // RNE
    return (short)(r >> 16);
}
__device__ __forceinline__ float bf2f(short h) {
    union { unsigned u; float f; } v;
    v.u = ((unsigned)(unsigned short)h) << 16;
    return v.f;
}

__device__ __forceinline__ void rope_rotate(float& x0, float& x1, int j, int pos) {
    double inv = pow(10000.0, -(double)j / 32.0);
    double ang = (double)pos * inv;
    float c = (float)cos(ang), s = (float)sin(ang);
    float r0 = x0 * c - x1 * s;
    float r1 = x1 * c + x0 * s;
    x0 = r0; x1 = r1;
}

// Pack hidden[64][4096] f32 -> fragment-major bf16 hi/lo (round-11).
__global__ __launch_bounds__(256) void prep_hilo_pk(
    const float* __restrict__ x, unsigned short* __restrict__ hi,
    unsigned short* __restrict__ lo)
{
    const int id = blockIdx.x * 256 + threadIdx.x;
    const int lane = id & 63;
    const int mtkt = id >> 6;
    const int mt = mtkt & 3;
    const int kt = mtkt >> 2;
    const int m = mt * 16 + (lane & 15);
    const int kk = kt * 32 + (lane >> 4) * 8;
    const float* src = &x[(size_t)m * KDIM + kk];
    float4 a = *(const float4*)src;
    float4 b = *(const float4*)(src + 4);
    float vf[8] = {a.x, a.y, a.z, a.w, b.x, b.y, b.z, b.w};
    unsigned short hbuf[8], lbuf[8];
    #pragma unroll
    for (int e = 0; e < 8; ++e) {
        short hh = f2bf(vf[e]);
        hbuf[e] = (unsigned short)hh;
        lbuf[e] = (unsigned short)f2bf(vf[e] - bf2f(hh));
    }
    *(int4*)&hi[(size_t)id * 8] = *(int4*)hbuf;
    *(int4*)&lo[(size_t)id * 8] = *(int4*)lbuf;
}

// MFMA split-K GEMM (round-11 verbatim).
__global__ __launch_bounds__(256) void gemm_mfma(
    const unsigned short* __restrict__ A_hi, const unsigned short* __restrict__ A_lo,
    const float* __restrict__ W, float* __restrict__ part, int N)
{
    const int tid = threadIdx.x;
    const int wv = tid >> 6;
    const int l = tid & 63;
    const int lr = l & 15;
    const int h = l >> 4;
    const int n0 = blockIdx.x * 64 + wv * 16;
    const int ks = blockIdx.y;
    const int k0 = ks * KRANGE;

    const float* wrow = &W[(size_t)(n0 + lr) * KDIM + h * 8];
    const size_t abase = (size_t)ks * 8 * 4 * 512 + (size_t)l * 8;

    f32x4 acc[4];
    #pragma unroll
    for (int mt = 0; mt < 4; ++mt) acc[mt] = (f32x4){0.f, 0.f, 0.f, 0.f};

    float4 w00, w01, w10, w11;
    bh8 ahc[4], alc[4], ahn[4], aln[4];

    w00 = *(const float4*)&wrow[k0];
    w01 = *(const float4*)&wrow[k0 + 4];
    w10 = *(const float4*)&wrow[k0 + 32];
    w11 = *(const float4*)&wrow[k0 + 36];
    #pragma unroll
    for (int mt = 0; mt < 4; ++mt) {
        ahc[mt] = *(const bh8*)&A_hi[abase + (size_t)mt * 512];
        alc[mt] = *(const bh8*)&A_lo[abase + (size_t)mt * 512];
    }

    auto body = [&](float4& pwa, float4& pwb, int kt) {
        float4 cw0 = pwa, cw1 = pwb;
        if (kt + 2 < 8) {
            pwa = *(const float4*)&wrow[k0 + (kt + 2) * 32];
            pwb = *(const float4*)&wrow[k0 + (kt + 2) * 32 + 4];
        }
        if (kt + 1 < 8) {
            const size_t an = abase + (size_t)(kt + 1) * 2048;
            #pragma unroll
            for (int mt = 0; mt < 4; ++mt) {
                ahn[mt] = *(const bh8*)&A_hi[an + (size_t)mt * 512];
                aln[mt] = *(const bh8*)&A_lo[an + (size_t)mt * 512];
            }
        }
        bh8 whi, wlo;
        float wf[8] = {cw0.x, cw0.y, cw0.z, cw0.w, cw1.x, cw1.y, cw1.z, cw1.w};
        #pragma unroll
        for (int e = 0; e < 8; ++e) {
            short hh = f2bf(wf[e]);
            whi[e] = hh;
            wlo[e] = f2bf(wf[e] - bf2f(hh));
        }
        #pragma unroll
        for (int mt = 0; mt < 4; ++mt) {
            acc[mt] = __builtin_amdgcn_mfma_f32_16x16x32_bf16(ahc[mt], whi, acc[mt], 0, 0, 0);
            acc[mt] = __builtin_amdgcn_mfma_f32_16x16x32_bf16(alc[mt], whi, acc[mt], 0, 0, 0);
            acc[mt] = __builtin_amdgcn_mfma_f32_16x16x32_bf16(ahc[mt], wlo, acc[mt], 0, 0, 0);
        }
        if (kt + 1 < 8) {
            #pragma unroll
            for (int mt = 0; mt < 4; ++mt) { ahc[mt] = ahn[mt]; alc[mt] = aln[mt]; }
        }
    };

    for (int kt2 = 0; kt2 < 4; ++kt2) {
        body(w00, w01, kt2 * 2);
        body(w10, w11, kt2 * 2 + 1);
    }

    #pragma unroll
    for (int mt = 0; mt < 4; ++mt) {
        const int m = mt * 16 + h * 4;
        #pragma unroll
        for (int j = 0; j < 4; ++j)
            part[((size_t)ks * 64 + m + j) * N + n0 + lr] = acc[mt][j];
    }
}

__global__ __launch_bounds__(256) void reduce_qkv(
    const float* __restrict__ part, const int* __restrict__ lens,
    float* __restrict__ q_rope, float* __restrict__ knew, float* __restrict__ vnew)
{
    const int b = blockIdx.y;
    const int c0 = (blockIdx.x * 256 + threadIdx.x) * 2;
    float x0 = 0.f, x1 = 0.f;
    #pragma unroll
    for (int ks = 0; ks < KSPLIT; ++ks) {
        float2 v = *(const float2*)&part[((size_t)ks * 64 + b) * NQKV + c0];
        x0 += v.x; x1 += v.y;
    }
    const int pos = lens[b] - 1;
    if (c0 < 4096) {
        const int d = c0 & 127;
        if (d < 64) rope_rotate(x0, x1, d >> 1, pos);
        q_rope[(size_t)b * 4096 + c0] = x0;
        q_rope[(size_t)b * 4096 + c0 + 1] = x1;
    } else if (c0 < 4352) {
        const int kidx = c0 - 4096, kh = kidx >> 7, d = kidx & 127;
        if (d < 64) rope_rotate(x0, x1, d >> 1, pos);
        knew[(b * 2 + kh) * 128 + d] = x0;
        knew[(b * 2 + kh) * 128 + d + 1] = x1;
    } else {
        const int vidx = c0 - 4352, kh = vidx >> 7, d = vidx & 127;
        vnew[(b * 2 + kh) * 128 + d] = x0;
        vnew[(b * 2 + kh) * 128 + d + 1] = x1;
    }
}

// MFMA flash-decode, 32-way independent partials, packed V.
// NO min-waves launch bound: let the allocator settle (~85-100 VGPR)
// instead of forcing spills (round-13 lesson: VGPR 48, 128 MB scratch).
__global__ __launch_bounds__(256) void attn_mfma(
    const float* __restrict__ qr, const float* __restrict__ knew,
    const float* __restrict__ vnew, const float* __restrict__ kcache,
    const float* __restrict__ vcache, const int* __restrict__ bt,
    const int* __restrict__ lens, float* __restrict__ pO, float* __restrict__ pML)
{
    const int split = blockIdx.x;
    const int kh = blockIdx.y;
    const int b = blockIdx.z;
    const int tid = threadIdx.x;
    const int wv = tid >> 6;
    const int l = tid & 63;
    const int g = l & 15;
    const int h = l >> 4;
    const int way = split * 4 + wv;

    __shared__ unsigned int sP[4][256];

    const int len = lens[b];
    const int nchunks = (len + 31) >> 5;   // len>=1024 -> nchunks>=32=WAYS
    const size_t nbase = ((size_t)(b * 2 + kh)) * 128;

    const float scale = 0.08838834764831845f;
    bh8 qf[4];
    {
        const float* qrow = &qr[((size_t)(b * 32 + kh * 16 + g)) * 128 + h * 8];
        #pragma unroll
        for (int dc = 0; dc < 4; ++dc) {
            float4 a = *(const float4*)&qrow[dc * 32];
            float4 c = *(const float4*)&qrow[dc * 32 + 4];
            qf[dc][0] = f2bf(a.x * scale); qf[dc][1] = f2bf(a.y * scale);
            qf[dc][2] = f2bf(a.z * scale); qf[dc][3] = f2bf(a.w * scale);
            qf[dc][4] = f2bf(c.x * scale); qf[dc][5] = f2bf(c.y * scale);
            qf[dc][6] = f2bf(c.z * scale); qf[dc][7] = f2bf(c.w * scale);
        }
    }

    float m = -INFINITY, lacc = 0.f;
    f32x4 oacc[8];
    #pragma unroll
    for (int dt = 0; dt < 8; ++dt) oacc[dt] = (f32x4){0.f, 0.f, 0.f, 0.f};

    for (int c = way; c < nchunks; c += WAYS) {
        const int s0 = c * 32;
        const int blk0 = bt[b * MAXPB + 2 * c];
        const int blk1 = bt[b * MAXPB + 2 * c + 1];

        // ---- K loads (f32 staging, converted after)
        const float* rowK0 = (s0 + g == len - 1) ? &knew[nbase]
            : &kcache[(((size_t)blk0 * 16 + g) * 2 + kh) * 128];
        const float* rowK1 = (s0 + 16 + g == len - 1) ? &knew[nbase]
            : &kcache[(((size_t)blk1 * 16 + g) * 2 + kh) * 128];
        float4 k0[8], k1[8];
        #pragma unroll
        for (int dc = 0; dc < 4; ++dc) {
            k0[2*dc]   = *(const float4*)&rowK0[dc * 32 + h * 8];
            k0[2*dc+1] = *(const float4*)&rowK0[dc * 32 + h * 8 + 4];
            k1[2*dc]   = *(const float4*)&rowK1[dc * 32 + h * 8];
            k1[2*dc+1] = *(const float4*)&rowK1[dc * 32 + h * 8 + 4];
        }

        // ---- V loads: convert to bf16 at load, packed [dt][4x u32]
        unsigned vw[8][4];
        #pragma unroll
        for (int e = 0; e < 8; ++e) {
            const int p = h * 8 + e;
            const int s = s0 + p;
            const float* rowV = (s == len - 1) ? &vnew[nbase]
                : &vcache[(((size_t)(p < 16 ? blk0 : blk1) * 16 + (p & 15)) * 2 + kh) * 128];
            #pragma unroll
            for (int dt = 0; dt < 8; ++dt) {
                unsigned short bb = (unsigned short)f2bf(rowV[dt * 16 + g]);
                if (e & 1) vw[dt][e >> 1] |= ((unsigned)bb << 16);
                else       vw[dt][e >> 1] = bb;
            }
        }

        // ---- QK^T
        f32x4 sa0 = (f32x4){0.f,0.f,0.f,0.f};
        f32x4 sa1 = (f32x4){0.f,0.f,0.f,0.f};
        #pragma unroll
        for (int dc = 0; dc < 4; ++dc) {
            bh8 a0, a1;
            a0[0]=f2bf(k0[2*dc].x);   a0[1]=f2bf(k0[2*dc].y);
            a0[2]=f2bf(k0[2*dc].z);   a0[3]=f2bf(k0[2*dc].w);
            a0[4]=f2bf(k0[2*dc+1].x); a0[5]=f2bf(k0[2*dc+1].y);
            a0[6]=f2bf(k0[2*dc+1].z); a0[7]=f2bf(k0[2*dc+1].w);
            a1[0]=f2bf(k1[2*dc].x);   a1[1]=f2bf(k1[2*dc].y);
            a1[2]=f2bf(k1[2*dc].z);   a1[3]=f2bf(k1[2*dc].w);
            a1[4]=f2bf(k1[2*dc+1].x); a1[5]=f2bf(k1[2*dc+1].y);
            a1[6]=f2bf(k1[2*dc+1].z); a1[7]=f2bf(k1[2*dc+1].w);
            sa0 = __builtin_amdgcn_mfma_f32_16x16x32_bf16(a0, qf[dc], sa0, 0, 0, 0);
            sa1 = __builtin_amdgcn_mfma_f32_16x16x32_bf16(a1, qf[dc], sa1, 0, 0, 0);
        }

        // ---- online softmax
        float sc[8];
        #pragma unroll
        for (int j = 0; j < 4; ++j) {
            sc[j]     = (s0 + 4*h + j      < len) ? sa0[j] : -INFINITY;
            sc[4 + j] = (s0 + 16 + 4*h + j < len) ? sa1[j] : -INFINITY;
        }
        float tmax = sc[0];
        #pragma unroll
        for (int j = 1; j < 8; ++j) tmax = fmaxf(tmax, sc[j]);
        tmax = fmaxf(tmax, __shfl_xor(tmax, 16));
        tmax = fmaxf(tmax, __shfl_xor(tmax, 32));
        const float m_new = fmaxf(m, tmax);
        const float corr = expf(m - m_new);
        float pe[8], ls = 0.f;
        #pragma unroll
        for (int j = 0; j < 8; ++j) { pe[j] = expf(sc[j] - m_new); ls += pe[j]; }
        ls += __shfl_xor(ls, 16);
        ls += __shfl_xor(ls, 32);
        lacc = lacc * corr + ls;
        m = m_new;
        #pragma unroll
        for (int dt = 0; dt < 8; ++dt) {
            oacc[dt][0] *= corr; oacc[dt][1] *= corr;
            oacc[dt][2] *= corr; oacc[dt][3] *= corr;
        }

        // ---- P relay via LDS (wave-local)
        unsigned int* myP = sP[wv];
        #pragma unroll
        for (int ph = 0; ph < 2; ++ph)
            #pragma unroll
            for (int t2 = 0; t2 < 2; ++t2) {
                unsigned lo = (unsigned short)f2bf(pe[ph*4 + 2*t2]);
                unsigned hi = (unsigned short)f2bf(pe[ph*4 + 2*t2 + 1]);
                myP[g * 16 + ph * 8 + 2 * h + t2] = lo | (hi << 16);
            }
        asm volatile("s_waitcnt lgkmcnt(0)" ::: "memory");
        bh8 pf = *(const bh8*)&myP[g * 16 + 4 * h];

        // ---- PV (V already bf16-packed)
        #pragma unroll
        for (int dt = 0; dt < 8; ++dt) {
            union { unsigned u[4]; bh8 v; } cvt;
            cvt.u[0] = vw[dt][0]; cvt.u[1] = vw[dt][1];
            cvt.u[2] = vw[dt][2]; cvt.u[3] = vw[dt][3];
            oacc[dt] = __builtin_amdgcn_mfma_f32_16x16x32_bf16(cvt.v, pf, oacc[dt], 0, 0, 0);
        }
    }

    // ---- every wave writes its own way slot (no block merge)
    size_t base = ((((size_t)(b * 2 + kh)) * 32 + way) * 16 + g) * 128;
    #pragma unroll
    for (int dt = 0; dt < 8; ++dt)
        #pragma unroll
        for (int j = 0; j < 4; ++j)
            pO[base + dt*16 + 4*h + j] = oacc[dt][j];
    if (l < 16) {
        size_t mb = ((((size_t)(b * 2 + kh)) * 32 + way) * 16 + g) * 2;
        pML[mb] = m;
        pML[mb + 1] = lacc;
    }
}

// Combine 32 ways; emit dense-GEMM input in PACKED frag-major hi/lo layout.
__global__ __launch_bounds__(128) void attn_combine(
    const float* __restrict__ pO, const float* __restrict__ pML,
    unsigned short* __restrict__ a_hi, unsigned short* __restrict__ a_lo)
{
    const int bk = blockIdx.x;
    const int half = blockIdx.y;
    const int tid = threadIdx.x;
    const int g = tid >> 3;
    const int dh = half * 8 + (tid & 7);

    float M = -INFINITY;
    #pragma unroll
    for (int s = 0; s < 32; ++s)
        M = fmaxf(M, pML[(((size_t)bk * 32 + s) * 16 + g) * 2]);

    float L = 0.f;
    float acc[8] = {0, 0, 0, 0, 0, 0, 0, 0};
    #pragma unroll 4
    for (int s = 0; s < 32; ++s) {
        size_t mb = (((size_t)bk * 32 + s) * 16 + g) * 2;
        float w = expf(pML[mb] - M);
        L += pML[mb + 1] * w;
        const float* src = &pO[(((size_t)bk * 32 + s) * 16 + g) * 128 + dh * 8];
        #pragma unroll
        for (int r = 0; r < 8; ++r) acc[r] += w * src[r];
    }
    const float invL = 1.f / L;
    const int b = bk >> 1, kh = bk & 1;
    const int k0 = (kh * 16 + g) * 128 + dh * 8;
    const int kt = k0 >> 5;
    const int h2 = dh & 3;
    const size_t didx = (((size_t)(kt * 4 + (b >> 4))) * 64 + h2 * 16 + (b & 15)) * 8;
    unsigned short hbuf[8], lbuf[8];
    #pragma unroll
    for (int r = 0; r < 8; ++r) {
        float o = acc[r] * invL;
        short hh = f2bf(o);
        hbuf[r] = (unsigned short)hh;
        lbuf[r] = (unsigned short)f2bf(o - bf2f(hh));
    }
    *(int4*)&a_hi[didx] = *(int4*)hbuf;
    *(int4*)&a_lo[didx] = *(int4*)lbuf;
}

__global__ __launch_bounds__(256) void reduce_dense(
    const float* __restrict__ part, float* __restrict__ out)
{
    const int b = blockIdx.y;
    const int col = (blockIdx.x * 256 + threadIdx.x) * 4;
    float4 s = make_float4(0.f, 0.f, 0.f, 0.f);
    #pragma unroll
    for (int ks = 0; ks < KSPLIT; ++ks) {
        float4 v = *(const float4*)&part[((size_t)ks * 64 + b) * NDENSE + col];
        s.x += v.x; s.y += v.y; s.z += v.z; s.w += v.w;
    }
    *(float4*)&out[(size_t)b * 4096 + col] = s;
}

extern "C" void kernel_launch(void* const* d_in, const int* in_sizes, int n_in,
                              void* d_out, int out_size, void* d_ws, size_t ws_size,
                              hipStream_t stream) {
    const float* hidden = (const float*)d_in[0];
    const float* wqkv   = (const float*)d_in[1];
    const float* wdense = (const float*)d_in[2];
    const float* kcache = (const float*)d_in[3];
    const float* vcache = (const float*)d_in[4];
    const int*   bt     = (const int*)d_in[5];
    const int*   lens   = (const int*)d_in[7];
    float* out = (float*)d_out;

    float* ws     = (float*)d_ws;
    float* q_rope = ws;                       // 262144 f
    float* k_new  = ws + 262144;              // 16384 f
    float* v_new  = ws + 278528;              // 16384 f
    unsigned short* A_hi = (unsigned short*)(ws + 294912);   // packed
    unsigned short* A_lo = A_hi + 262144;                    // packed
    float* regX   = ws + 557056;              // gemm partials (<=4718592 f) / pO
    float* pO     = regX;                     // 64*2*32*16*128 = 8388608 f
    float* pML    = ws + 557056 + 8388608;    // 131072 f
    // total ws use: 9076736 floats = 36.3 MB

    prep_hilo_pk<<<dim3(128), dim3(256), 0, stream>>>(hidden, A_hi, A_lo);
    gemm_mfma<<<dim3(NQKV / 64, KSPLIT), dim3(256), 0, stream>>>(
        A_hi, A_lo, wqkv, regX, NQKV);
    reduce_qkv<<<dim3(9, 64), dim3(256), 0, stream>>>(
        regX, lens, q_rope, k_new, v_new);
    attn_mfma<<<dim3(SPLITS, 2, 64), dim3(256), 0, stream>>>(
        q_rope, k_new, v_new, kcache, vcache, bt, lens, pO, pML);
    attn_combine<<<dim3(128, 2), dim3(128), 0, stream>>>(pO, pML, A_hi, A_lo);
    gemm_mfma<<<dim3(NDENSE / 64, KSPLIT), dim3(256), 0, stream>>>(
        A_hi, A_lo, wdense, regX, NDENSE);
    reduce_dense<<<dim3(4, 64), dim3(256), 0, stream>>>(regX, out);
}

// Round 15
// 169.621 us; speedup vs baseline: 3.7480x; 1.0347x over previous
//
#include <hip/hip_runtime.h>
#include <math.h>

#define KDIM 4096
#define SPLITS 8
#define WAYS 32
#define MAXPB 256
#define NQKV 4608
#define NDENSE 4096
#define KSPLIT 16
#define KRANGE 256

typedef __attribute__((ext_vector_type(8))) short bh8;
typedef __attribute__((ext_vector_type(4))) float f32x4;

__device__ __forceinline__ short f2bf(float x) {
    union { float f; unsigned u; } v; v.f = x;
    unsigned r = v.u + 0x7FFFu + ((v.u >> 16) & 1u);   // RNE
    return (short)(r >> 16);
}
__device__ __forceinline__ float bf2f(short h) {
    union { unsigned u; float f; } v;
    v.u = ((unsigned)(unsigned short)h) << 16;
    return v.f;
}

__device__ __forceinline__ void rope_rotate(float& x0, float& x1, int j, int pos) {
    double inv = pow(10000.0, -(double)j / 32.0);
    double ang = (double)pos * inv;
    float c = (float)cos(ang), s = (float)sin(ang);
    float r0 = x0 * c - x1 * s;
    float r1 = x1 * c + x0 * s;
    x0 = r0; x1 = r1;
}

// Pack hidden[64][4096] f32 -> fragment-major bf16 hi/lo:
// cell (kt, mt), lane l holds A[mt*16 + (l&15)][kt*32 + (l>>4)*8 .. +8].
__global__ __launch_bounds__(256) void prep_hilo_pk(
    const float* __restrict__ x, unsigned short* __restrict__ hi,
    unsigned short* __restrict__ lo)
{
    const int id = blockIdx.x * 256 + threadIdx.x;
    const int lane = id & 63;
    const int mtkt = id >> 6;
    const int mt = mtkt & 3;
    const int kt = mtkt >> 2;
    const int m = mt * 16 + (lane & 15);
    const int kk = kt * 32 + (lane >> 4) * 8;
    const float* src = &x[(size_t)m * KDIM + kk];
    float4 a = *(const float4*)src;
    float4 b = *(const float4*)(src + 4);
    float vf[8] = {a.x, a.y, a.z, a.w, b.x, b.y, b.z, b.w};
    unsigned short hbuf[8], lbuf[8];
    #pragma unroll
    for (int e = 0; e < 8; ++e) {
        short hh = f2bf(vf[e]);
        hbuf[e] = (unsigned short)hh;
        lbuf[e] = (unsigned short)f2bf(vf[e] - bf2f(hh));
    }
    *(int4*)&hi[(size_t)id * 8] = *(int4*)hbuf;
    *(int4*)&lo[(size_t)id * 8] = *(int4*)lbuf;
}

// MFMA split-K GEMM, packed-A frag loads (1 txn/load), W prefetch depth 2.
// KSPLIT=16 -> 1152/1024 blocks -> ~16 resident waves/CU. (round-11)
__global__ __launch_bounds__(256) void gemm_mfma(
    const unsigned short* __restrict__ A_hi, const unsigned short* __restrict__ A_lo,
    const float* __restrict__ W, float* __restrict__ part, int N)
{
    const int tid = threadIdx.x;
    const int wv = tid >> 6;
    const int l = tid & 63;
    const int lr = l & 15;
    const int h = l >> 4;
    const int n0 = blockIdx.x * 64 + wv * 16;
    const int ks = blockIdx.y;
    const int k0 = ks * KRANGE;

    const float* wrow = &W[(size_t)(n0 + lr) * KDIM + h * 8];
    const size_t abase = (size_t)ks * 8 * 4 * 512 + (size_t)l * 8;

    f32x4 acc[4];
    #pragma unroll
    for (int mt = 0; mt < 4; ++mt) acc[mt] = (f32x4){0.f, 0.f, 0.f, 0.f};

    float4 w00, w01, w10, w11;
    bh8 ahc[4], alc[4], ahn[4], aln[4];

    w00 = *(const float4*)&wrow[k0];
    w01 = *(const float4*)&wrow[k0 + 4];
    w10 = *(const float4*)&wrow[k0 + 32];
    w11 = *(const float4*)&wrow[k0 + 36];
    #pragma unroll
    for (int mt = 0; mt < 4; ++mt) {
        ahc[mt] = *(const bh8*)&A_hi[abase + (size_t)mt * 512];
        alc[mt] = *(const bh8*)&A_lo[abase + (size_t)mt * 512];
    }

    auto body = [&](float4& pwa, float4& pwb, int kt) {
        float4 cw0 = pwa, cw1 = pwb;
        if (kt + 2 < 8) {
            pwa = *(const float4*)&wrow[k0 + (kt + 2) * 32];
            pwb = *(const float4*)&wrow[k0 + (kt + 2) * 32 + 4];
        }
        if (kt + 1 < 8) {
            const size_t an = abase + (size_t)(kt + 1) * 2048;
            #pragma unroll
            for (int mt = 0; mt < 4; ++mt) {
                ahn[mt] = *(const bh8*)&A_hi[an + (size_t)mt * 512];
                aln[mt] = *(const bh8*)&A_lo[an + (size_t)mt * 512];
            }
        }
        bh8 whi, wlo;
        float wf[8] = {cw0.x, cw0.y, cw0.z, cw0.w, cw1.x, cw1.y, cw1.z, cw1.w};
        #pragma unroll
        for (int e = 0; e < 8; ++e) {
            short hh = f2bf(wf[e]);
            whi[e] = hh;
            wlo[e] = f2bf(wf[e] - bf2f(hh));
        }
        #pragma unroll
        for (int mt = 0; mt < 4; ++mt) {
            acc[mt] = __builtin_amdgcn_mfma_f32_16x16x32_bf16(ahc[mt], whi, acc[mt], 0, 0, 0);
            acc[mt] = __builtin_amdgcn_mfma_f32_16x16x32_bf16(alc[mt], whi, acc[mt], 0, 0, 0);
            acc[mt] = __builtin_amdgcn_mfma_f32_16x16x32_bf16(ahc[mt], wlo, acc[mt], 0, 0, 0);
        }
        if (kt + 1 < 8) {
            #pragma unroll
            for (int mt = 0; mt < 4; ++mt) { ahc[mt] = ahn[mt]; alc[mt] = aln[mt]; }
        }
    };

    for (int kt2 = 0; kt2 < 4; ++kt2) {
        body(w00, w01, kt2 * 2);
        body(w10, w11, kt2 * 2 + 1);
    }

    #pragma unroll
    for (int mt = 0; mt < 4; ++mt) {
        const int m = mt * 16 + h * 4;
        #pragma unroll
        for (int j = 0; j < 4; ++j)
            part[((size_t)ks * 64 + m + j) * N + n0 + lr] = acc[mt][j];
    }
}

__global__ __launch_bounds__(256) void reduce_qkv(
    const float* __restrict__ part, const int* __restrict__ lens,
    float* __restrict__ q_rope, float* __restrict__ knew, float* __restrict__ vnew)
{
    const int b = blockIdx.y;
    const int c0 = (blockIdx.x * 256 + threadIdx.x) * 2;
    float x0 = 0.f, x1 = 0.f;
    #pragma unroll
    for (int ks = 0; ks < KSPLIT; ++ks) {
        float2 v = *(const float2*)&part[((size_t)ks * 64 + b) * NQKV + c0];
        x0 += v.x; x1 += v.y;
    }
    const int pos = lens[b] - 1;
    if (c0 < 4096) {
        const int d = c0 & 127;
        if (d < 64) rope_rotate(x0, x1, d >> 1, pos);
        q_rope[(size_t)b * 4096 + c0] = x0;
        q_rope[(size_t)b * 4096 + c0 + 1] = x1;
    } else if (c0 < 4352) {
        const int kidx = c0 - 4096, kh = kidx >> 7, d = kidx & 127;
        if (d < 64) rope_rotate(x0, x1, d >> 1, pos);
        knew[(b * 2 + kh) * 128 + d] = x0;
        knew[(b * 2 + kh) * 128 + d + 1] = x1;
    } else {
        const int vidx = c0 - 4352, kh = vidx >> 7, d = vidx & 127;
        vnew[(b * 2 + kh) * 128 + d] = x0;
        vnew[(b * 2 + kh) * 128 + d + 1] = x1;
    }
}

// MFMA flash-decode (round-5/11 known-best, verbatim).
__global__ __launch_bounds__(256) void attn_mfma(
    const float* __restrict__ qr, const float* __restrict__ knew,
    const float* __restrict__ vnew, const float* __restrict__ kcache,
    const float* __restrict__ vcache, const int* __restrict__ bt,
    const int* __restrict__ lens, float* __restrict__ pO, float* __restrict__ pML)
{
    const int split = blockIdx.x;
    const int kh = blockIdx.y;
    const int b = blockIdx.z;
    const int tid = threadIdx.x;
    const int wv = tid >> 6;
    const int l = tid & 63;
    const int g = l & 15;
    const int h = l >> 4;
    const int way = split * 4 + wv;

    __shared__ unsigned int sP[4][256];
    __shared__ float sO[3][16][132];
    __shared__ float sML[3][2][16];

    const int len = lens[b];
    const int nchunks = (len + 31) >> 5;
    const size_t nbase = ((size_t)(b * 2 + kh)) * 128;

    const float scale = 0.08838834764831845f;
    bh8 qf[4];
    {
        const float* qrow = &qr[((size_t)(b * 32 + kh * 16 + g)) * 128 + h * 8];
        #pragma unroll
        for (int dc = 0; dc < 4; ++dc) {
            float4 a = *(const float4*)&qrow[dc * 32];
            float4 c = *(const float4*)&qrow[dc * 32 + 4];
            qf[dc][0] = f2bf(a.x * scale); qf[dc][1] = f2bf(a.y * scale);
            qf[dc][2] = f2bf(a.z * scale); qf[dc][3] = f2bf(a.w * scale);
            qf[dc][4] = f2bf(c.x * scale); qf[dc][5] = f2bf(c.y * scale);
            qf[dc][6] = f2bf(c.z * scale); qf[dc][7] = f2bf(c.w * scale);
        }
    }

    float m = -INFINITY, lacc = 0.f;
    f32x4 oacc[8];
    #pragma unroll
    for (int dt = 0; dt < 8; ++dt) oacc[dt] = (f32x4){0.f, 0.f, 0.f, 0.f};

    for (int c = way; c < nchunks; c += WAYS) {
        const int s0 = c * 32;
        const int blk0 = bt[b * MAXPB + 2 * c];
        const int blk1 = bt[b * MAXPB + 2 * c + 1];

        const float* rowK0 = (s0 + g == len - 1) ? &knew[nbase]
            : &kcache[(((size_t)blk0 * 16 + g) * 2 + kh) * 128];
        const float* rowK1 = (s0 + 16 + g == len - 1) ? &knew[nbase]
            : &kcache[(((size_t)blk1 * 16 + g) * 2 + kh) * 128];
        float4 k0[8], k1[8];
        #pragma unroll
        for (int dc = 0; dc < 4; ++dc) {
            k0[2*dc]   = *(const float4*)&rowK0[dc * 32 + h * 8];
            k0[2*dc+1] = *(const float4*)&rowK0[dc * 32 + h * 8 + 4];
            k1[2*dc]   = *(const float4*)&rowK1[dc * 32 + h * 8];
            k1[2*dc+1] = *(const float4*)&rowK1[dc * 32 + h * 8 + 4];
        }

        float vv[8][8];
        #pragma unroll
        for (int e = 0; e < 8; ++e) {
            const int p = h * 8 + e;
            const int s = s0 + p;
            const float* rowV = (s == len - 1) ? &vnew[nbase]
                : &vcache[(((size_t)(p < 16 ? blk0 : blk1) * 16 + (p & 15)) * 2 + kh) * 128];
            #pragma unroll
            for (int dt = 0; dt < 8; ++dt)
                vv[e][dt] = rowV[dt * 16 + g];
        }

        f32x4 sa0 = (f32x4){0.f,0.f,0.f,0.f};
        f32x4 sa1 = (f32x4){0.f,0.f,0.f,0.f};
        #pragma unroll
        for (int dc = 0; dc < 4; ++dc) {
            bh8 a0, a1;
            a0[0]=f2bf(k0[2*dc].x);   a0[1]=f2bf(k0[2*dc].y);
            a0[2]=f2bf(k0[2*dc].z);   a0[3]=f2bf(k0[2*dc].w);
            a0[4]=f2bf(k0[2*dc+1].x); a0[5]=f2bf(k0[2*dc+1].y);
            a0[6]=f2bf(k0[2*dc+1].z); a0[7]=f2bf(k0[2*dc+1].w);
            a1[0]=f2bf(k1[2*dc].x);   a1[1]=f2bf(k1[2*dc].y);
            a1[2]=f2bf(k1[2*dc].z);   a1[3]=f2bf(k1[2*dc].w);
            a1[4]=f2bf(k1[2*dc+1].x); a1[5]=f2bf(k1[2*dc+1].y);
            a1[6]=f2bf(k1[2*dc+1].z); a1[7]=f2bf(k1[2*dc+1].w);
            sa0 = __builtin_amdgcn_mfma_f32_16x16x32_bf16(a0, qf[dc], sa0, 0, 0, 0);
            sa1 = __builtin_amdgcn_mfma_f32_16x16x32_bf16(a1, qf[dc], sa1, 0, 0, 0);
        }

        float sc[8];
        #pragma unroll
        for (int j = 0; j < 4; ++j) {
            sc[j]     = (s0 + 4*h + j      < len) ? sa0[j] : -INFINITY;
            sc[4 + j] = (s0 + 16 + 4*h + j < len) ? sa1[j] : -INFINITY;
        }
        float tmax = sc[0];
        #pragma unroll
        for (int j = 1; j < 8; ++j) tmax = fmaxf(tmax, sc[j]);
        tmax = fmaxf(tmax, __shfl_xor(tmax, 16));
        tmax = fmaxf(tmax, __shfl_xor(tmax, 32));
        const float m_new = fmaxf(m, tmax);
        const float corr = expf(m - m_new);
        float pe[8], ls = 0.f;
        #pragma unroll
        for (int j = 0; j < 8; ++j) { pe[j] = expf(sc[j] - m_new); ls += pe[j]; }
        ls += __shfl_xor(ls, 16);
        ls += __shfl_xor(ls, 32);
        lacc = lacc * corr + ls;
        m = m_new;
        #pragma unroll
        for (int dt = 0; dt < 8; ++dt) {
            oacc[dt][0] *= corr; oacc[dt][1] *= corr;
            oacc[dt][2] *= corr; oacc[dt][3] *= corr;
        }

        unsigned int* myP = sP[wv];
        #pragma unroll
        for (int ph = 0; ph < 2; ++ph)
            #pragma unroll
            for (int t2 = 0; t2 < 2; ++t2) {
                unsigned lo = (unsigned short)f2bf(pe[ph*4 + 2*t2]);
                unsigned hi = (unsigned short)f2bf(pe[ph*4 + 2*t2 + 1]);
                myP[g * 16 + ph * 8 + 2 * h + t2] = lo | (hi << 16);
            }
        asm volatile("s_waitcnt lgkmcnt(0)" ::: "memory");
        bh8 pf = *(const bh8*)&myP[g * 16 + 4 * h];

        #pragma unroll
        for (int dt = 0; dt < 8; ++dt) {
            bh8 av;
            #pragma unroll
            for (int e = 0; e < 8; ++e) av[e] = f2bf(vv[e][dt]);
            oacc[dt] = __builtin_amdgcn_mfma_f32_16x16x32_bf16(av, pf, oacc[dt], 0, 0, 0);
        }
    }

    if (wv > 0) {
        #pragma unroll
        for (int dt = 0; dt < 8; ++dt)
            #pragma unroll
            for (int j = 0; j < 4; ++j)
                sO[wv-1][g][dt*16 + 4*h + j] = oacc[dt][j];
        if (l < 16) {
            sML[wv-1][0][g] = m;
            sML[wv-1][1][g] = lacc;
        }
    }
    __syncthreads();
    if (wv == 0) {
        float M = m;
        #pragma unroll
        for (int i = 0; i < 3; ++i) M = fmaxf(M, sML[i][0][g]);
        const float w0 = expf(m - M);
        float L = lacc * w0;
        float wi[3];
        #pragma unroll
        for (int i = 0; i < 3; ++i) {
            wi[i] = expf(sML[i][0][g] - M);
            L += sML[i][1][g] * wi[i];
        }
        size_t base = ((((size_t)(b * 2 + kh)) * SPLITS + split) * 16 + g) * 128;
        #pragma unroll
        for (int dt = 0; dt < 8; ++dt)
            #pragma unroll
            for (int j = 0; j < 4; ++j) {
                float o = oacc[dt][j] * w0;
                #pragma unroll
                for (int i = 0; i < 3; ++i)
                    o += sO[i][g][dt*16 + 4*h + j] * wi[i];
                pO[base + dt*16 + 4*h + j] = o;
            }
        if (l < 16) {
            size_t mb = ((((size_t)(b * 2 + kh)) * SPLITS + split) * 16 + g) * 2;
            pML[mb] = M;
            pML[mb + 1] = L;
        }
    }
}

// Combine splits; emit dense-GEMM input in PACKED frag-major hi/lo layout.
__global__ __launch_bounds__(256) void attn_combine(
    const float* __restrict__ pO, const float* __restrict__ pML,
    unsigned short* __restrict__ a_hi, unsigned short* __restrict__ a_lo)
{
    const int bk = blockIdx.x;
    const int tid = threadIdx.x;
    const int g = tid >> 4;
    const int dh = tid & 15;

    float ms[SPLITS], ls[SPLITS];
    float M = -INFINITY;
    #pragma unroll
    for (int s = 0; s < SPLITS; ++s) {
        size_t mb = (((size_t)bk * SPLITS + s) * 16 + g) * 2;
        ms[s] = pML[mb]; ls[s] = pML[mb + 1];
        M = fmaxf(M, ms[s]);
    }
    float L = 0.f;
    #pragma unroll
    for (int s = 0; s < SPLITS; ++s) L += ls[s] * expf(ms[s] - M);

    float acc[8] = {0, 0, 0, 0, 0, 0, 0, 0};
    #pragma unroll
    for (int s = 0; s < SPLITS; ++s) {
        float wgt = expf(ms[s] - M);
        const float* src = &pO[(((size_t)bk * SPLITS + s) * 16 + g) * 128 + dh * 8];
        #pragma unroll
        for (int r = 0; r < 8; ++r) acc[r] += wgt * src[r];
    }
    const float invL = 1.f / L;
    const int b = bk >> 1, kh = bk & 1;
    const int k0 = (kh * 16 + g) * 128 + dh * 8;
    const int kt = k0 >> 5;
    const int h2 = dh & 3;
    const size_t didx = (((size_t)(kt * 4 + (b >> 4))) * 64 + h2 * 16 + (b & 15)) * 8;
    unsigned short hbuf[8], lbuf[8];
    #pragma unroll
    for (int r = 0; r < 8; ++r) {
        float o = acc[r] * invL;
        short hh = f2bf(o);
        hbuf[r] = (unsigned short)hh;
        lbuf[r] = (unsigned short)f2bf(o - bf2f(hh));
    }
    *(int4*)&a_hi[didx] = *(int4*)hbuf;
    *(int4*)&a_lo[didx] = *(int4*)lbuf;
}

__global__ __launch_bounds__(256) void reduce_dense(
    const float* __restrict__ part, float* __restrict__ out)
{
    const int b = blockIdx.y;
    const int col = (blockIdx.x * 256 + threadIdx.x) * 4;
    float4 s = make_float4(0.f, 0.f, 0.f, 0.f);
    #pragma unroll
    for (int ks = 0; ks < KSPLIT; ++ks) {
        float4 v = *(const float4*)&part[((size_t)ks * 64 + b) * NDENSE + col];
        s.x += v.x; s.y += v.y; s.z += v.z; s.w += v.w;
    }
    *(float4*)&out[(size_t)b * 4096 + col] = s;
}

extern "C" void kernel_launch(void* const* d_in, const int* in_sizes, int n_in,
                              void* d_out, int out_size, void* d_ws, size_t ws_size,
                              hipStream_t stream) {
    const float* hidden = (const float*)d_in[0];
    const float* wqkv   = (const float*)d_in[1];
    const float* wdense = (const float*)d_in[2];
    const float* kcache = (const float*)d_in[3];
    const float* vcache = (const float*)d_in[4];
    const int*   bt     = (const int*)d_in[5];
    const int*   lens   = (const int*)d_in[7];
    float* out = (float*)d_out;

    float* ws     = (float*)d_ws;
    float* q_rope = ws;                       // 262144 f
    float* k_new  = ws + 262144;              // 16384 f
    float* v_new  = ws + 278528;              // 16384 f
    unsigned short* A_hi = (unsigned short*)(ws + 294912);   // packed
    unsigned short* A_lo = A_hi + 262144;                    // packed
    float* regX   = ws + 557056;              // partials (<=4718592 f) / pO (2097152 f)
    float* pO     = regX;
    float* pML    = ws + 5275648;             // 32768 f
    // total ws use: 5308416 floats = 21.2 MB

    prep_hilo_pk<<<dim3(128), dim3(256), 0, stream>>>(hidden, A_hi, A_lo);
    gemm_mfma<<<dim3(NQKV / 64, KSPLIT), dim3(256), 0, stream>>>(
        A_hi, A_lo, wqkv, regX, NQKV);
    reduce_qkv<<<dim3(9, 64), dim3(256), 0, stream>>>(
        regX, lens, q_rope, k_new, v_new);
    attn_mfma<<<dim3(SPLITS, 2, 64), dim3(256), 0, stream>>>(
        q_rope, k_new, v_new, kcache, vcache, bt, lens, pO, pML);
    attn_combine<<<dim3(128), dim3(256), 0, stream>>>(pO, pML, A_hi, A_lo);
    gemm_mfma<<<dim3(NDENSE / 64, KSPLIT), dim3(256), 0, stream>>>(
        A_hi, A_lo, wdense, regX, NDENSE);
    reduce_dense<<<dim3(4, 64), dim3(256), 0, stream>>>(regX, out);
}